// Round 1
// baseline (241.392 us; speedup 1.0000x reference)
//
#include <hip/hip_runtime.h>

// CrossAttentionPlus: out = ( 0.5*softmax(causal(QK^T*s)+mask) + 0.5*supplied ) @ V, head-merged, @Wo + bo
// Normalization-after-mix skipped: denominator == 1 analytically (both terms are softmax outputs).
//
// Pipeline:
//   1) transpose_cvt: Wq,Wk,Wv,Wo fp32[1024,1024] -> bf16 W^T[1024,1024] (K-contiguous for GEMM B-operand)
//   2) gemm<AF32=true> x3: X fp32 -> (X@W) bf16, written as Qh/Kh [B,H,L,64] and VTh [B,H,64,L]
//   3) attn: per (b,h,qblock=64): flash softmax (online m,l) + fused supplied-attn branch
//   4) gemm<AF32=false>: ctx bf16 @ WoT -> d_out fp32 + bias

typedef __attribute__((ext_vector_type(8))) short short8;
typedef __attribute__((ext_vector_type(4))) short short4v;
typedef __attribute__((ext_vector_type(4))) float f32x4;

#define MFMA16(a,b,c) __builtin_amdgcn_mfma_f32_16x16x32_bf16(a,b,c,0,0,0)

__device__ __forceinline__ short f2bf(float f){
  union { float f; unsigned u; } x; x.f = f;
  unsigned r = x.u + 0x7FFFu + ((x.u >> 16) & 1u);
  return (short)(r >> 16);
}

// ---------------- weight transpose + convert: out[n][k] = bf16(in[k][n]) ----------------
__global__ void transpose_cvt_kernel(const float* __restrict__ in, short* __restrict__ out){
  __shared__ float tile[32][33];
  int bx = blockIdx.x*32, by = blockIdx.y*32;
  int tx = threadIdx.x, ty = threadIdx.y;   // block (32,8)
  #pragma unroll
  for (int i=0;i<32;i+=8) tile[ty+i][tx] = in[(size_t)(by+ty+i)*1024 + bx+tx];
  __syncthreads();
  #pragma unroll
  for (int i=0;i<32;i+=8) out[(size_t)(bx+ty+i)*1024 + by+tx] = f2bf(tile[tx][ty+i]);
}

// ---------------- GEMM: C[M=4096,N=1024] = A[M,1024] @ BT[N,1024]^T ----------------
// 128x128 tile, BK=64, 4 waves (2x2), 16x16x32 MFMA, XOR-swizzled LDS ((row&7)<<4 on 128B rows).
// mode 0/1: dstb = head layout [(b*16+h)*1024+l]*64+d    (Q, K)
// mode 2  : dstb = transposed  [(b*16+h)*64+d]*1024+l    (V^T)
// mode 3  : dstf = fp32 flat [m*1024+n] + bias[n]        (final output)
template<bool AF32>
__global__ __launch_bounds__(256) void gemm_kernel(
    const void* __restrict__ Ain, const short* __restrict__ BT,
    short* __restrict__ dstb, float* __restrict__ dstf,
    const float* __restrict__ bias, int mode)
{
  __shared__ short Asm[128*64];
  __shared__ short Bsm[128*64];
  int tid = threadIdx.x;
  int lane = tid & 63, w = tid >> 6;
  int wm = (w >> 1) * 64, wn = (w & 1) * 64;
  int bm = blockIdx.y * 128, bn = blockIdx.x * 128;

  const f32x4 z4 = {0.f,0.f,0.f,0.f};
  f32x4 acc[4][4];
  #pragma unroll
  for (int i=0;i<4;i++)
    #pragma unroll
    for (int j=0;j<4;j++) acc[i][j] = z4;

  short8 ra[4], rb[4], ra2[4], rb2[4];

  auto loadAB = [&](int kt, short8* pa, short8* pb){
    #pragma unroll
    for (int c=0;c<4;c++){
      int idx = tid + 256*c;
      int row = idx >> 3;
      int col = (idx & 7) * 8;
      if constexpr (AF32){
        const float* Af = (const float*)Ain;
        const float* p = Af + (size_t)(bm+row)*1024 + kt*64 + col;
        f32x4 a0 = *(const f32x4*)p;
        f32x4 a1 = *(const f32x4*)(p+4);
        short8 r;
        #pragma unroll
        for (int e=0;e<4;e++){ r[e]=f2bf(a0[e]); r[e+4]=f2bf(a1[e]); }
        pa[c] = r;
      } else {
        const short* Ab = (const short*)Ain;
        pa[c] = *(const short8*)(Ab + (size_t)(bm+row)*1024 + kt*64 + col);
      }
      pb[c] = *(const short8*)(BT + (size_t)(bn+row)*1024 + kt*64 + col);
    }
  };
  auto storeAB = [&](short8* pa, short8* pb){
    #pragma unroll
    for (int c=0;c<4;c++){
      int idx = tid + 256*c;
      int row = idx >> 3;
      int byte = row*128 + (((idx&7)*16) ^ ((row&7)<<4));
      *(short8*)((char*)Asm + byte) = pa[c];
      *(short8*)((char*)Bsm + byte) = pb[c];
    }
  };
  auto compute = [&](){
    #pragma unroll
    for (int kc=0;kc<2;kc++){
      short8 af[4], bf[4];
      #pragma unroll
      for (int i=0;i<4;i++){
        int rowa = wm + i*16 + (lane&15);
        af[i] = *(const short8*)((const char*)Asm + rowa*128 + ((kc*64 + ((lane>>4)*16)) ^ ((rowa&7)<<4)));
        int rowb = wn + i*16 + (lane&15);
        bf[i] = *(const short8*)((const char*)Bsm + rowb*128 + ((kc*64 + ((lane>>4)*16)) ^ ((rowb&7)<<4)));
      }
      #pragma unroll
      for (int i=0;i<4;i++)
        #pragma unroll
        for (int j=0;j<4;j++)
          acc[i][j] = MFMA16(af[i], bf[j], acc[i][j]);
    }
  };

  loadAB(0, ra, rb);
  for (int kt=0;;){
    __syncthreads();
    storeAB(ra, rb);
    __syncthreads();
    if (kt+1 < 16) loadAB(kt+1, ra2, rb2);
    compute();
    if (++kt >= 16) break;
    #pragma unroll
    for (int c=0;c<4;c++){ ra[c]=ra2[c]; rb[c]=rb2[c]; }
  }

  #pragma unroll
  for (int i=0;i<4;i++){
    #pragma unroll
    for (int j=0;j<4;j++){
      #pragma unroll
      for (int r=0;r<4;r++){
        int m = bm + wm + i*16 + ((lane>>4)*4) + r;
        int n = bn + wn + j*16 + (lane&15);
        float v = acc[i][j][r];
        if (mode == 3){
          dstf[(size_t)m*1024 + n] = v + bias[n];
        } else {
          int b = m >> 10, l = m & 1023, h = n >> 6, d = n & 63;
          int bh = b*16 + h;
          short bv = f2bf(v);
          if (mode == 2) dstb[((size_t)(bh*64 + d) << 10) + l] = bv;
          else           dstb[((size_t)(bh << 10) + l)*64 + d] = bv;
        }
      }
    }
  }
}

// ---------------- fused attention ----------------
// grid (qb=16, bh=64), block 256 = 4 waves; wave w owns q-rows q0w..q0w+15.
// ctx[b][q][h*64+d] = 0.5*softmax_row(QK^T*s + mask, causal) @ V  +  0.5*(causal supplied) @ V
__global__ __launch_bounds__(256) void attn_kernel(
    const short* __restrict__ Qh, const short* __restrict__ Kh,
    const short* __restrict__ VTh, const float* __restrict__ amask,
    const float* __restrict__ sup, short* __restrict__ ctx)
{
  __shared__ short Ksm[64*64];      // [k][d]  swizzled
  __shared__ short Vsm[64*64];      // [d][k]  swizzled
  __shared__ short Psm[4][16*64];   // per-wave P, swizzled
  int tid = threadIdx.x, lane = tid & 63, w = tid >> 6;
  int qb = blockIdx.x, bh = blockIdx.y;
  int b = bh >> 4, h = bh & 15;
  int q0w = qb*64 + w*16;

  const f32x4 z4 = {0.f,0.f,0.f,0.f};
  short8 qf[2];
  {
    const short* qp = Qh + ((size_t)bh*1024 + q0w + (lane&15))*64 + (lane>>4)*8;
    qf[0] = *(const short8*)qp;
    qf[1] = *(const short8*)(qp + 32);
  }
  f32x4 o_loc[4], o_sup[4];
  #pragma unroll
  for (int i=0;i<4;i++){ o_loc[i]=z4; o_sup[i]=z4; }
  float m_run[4], l_run[4];
  #pragma unroll
  for (int j=0;j<4;j++){ m_run[j]=-3e38f; l_run[j]=0.f; }

  const float* supq  = sup   + (size_t)bh*1024*1024;
  const float* maskb = amask + (size_t)b*1024*1024;

  short8 rk[2], rv[2], rk2[2], rv2[2];
  auto loadKV = [&](int t, short8* k8, short8* v8){
    int k0 = t*64;
    #pragma unroll
    for (int c=0;c<2;c++){
      int idx = tid + 256*c;
      int row = idx >> 3, col = (idx&7)*8;
      k8[c] = *(const short8*)(Kh  + ((size_t)bh*1024 + k0 + row)*64 + col);
      v8[c] = *(const short8*)(VTh + ((size_t)bh*64 + row)*1024 + k0 + col);
    }
  };
  auto storeKV = [&](short8* k8, short8* v8){
    #pragma unroll
    for (int c=0;c<2;c++){
      int idx = tid + 256*c;
      int row = idx >> 3;
      int byte = row*128 + (((idx&7)*16) ^ ((row&7)<<4));
      *(short8*)((char*)Ksm + byte) = k8[c];
      *(short8*)((char*)Vsm + byte) = v8[c];
    }
  };

  auto compute = [&](int t){
    int k0 = t*64;
    // S = Q K^T  (m=q-row, n=k-pos, contraction over d)
    f32x4 s[4];
    #pragma unroll
    for (int ni=0;ni<4;ni++) s[ni]=z4;
    #pragma unroll
    for (int kc=0;kc<2;kc++){
      #pragma unroll
      for (int ni=0;ni<4;ni++){
        int row = ni*16 + (lane&15);
        short8 kf = *(const short8*)((const char*)Ksm + row*128 + ((kc*64 + ((lane>>4)*16)) ^ ((row&7)<<4)));
        s[ni] = MFMA16(qf[kc], kf, s[ni]);
      }
    }
    // scale + additive mask + causal
    float sv[4][4];
    #pragma unroll
    for (int ni=0;ni<4;ni++){
      int k = k0 + ni*16 + (lane&15);
      #pragma unroll
      for (int j=0;j<4;j++){
        int q = q0w + (lane>>4)*4 + j;
        float v = s[ni][j]*0.125f + maskb[(size_t)q*1024 + k];
        sv[ni][j] = (k > q) ? -1e30f : v;
      }
    }
    // online softmax per row (row lives across 16 lanes of the group)
    #pragma unroll
    for (int j=0;j<4;j++){
      float rm = fmaxf(fmaxf(sv[0][j],sv[1][j]), fmaxf(sv[2][j],sv[3][j]));
      rm = fmaxf(rm, __shfl_xor(rm,1));
      rm = fmaxf(rm, __shfl_xor(rm,2));
      rm = fmaxf(rm, __shfl_xor(rm,4));
      rm = fmaxf(rm, __shfl_xor(rm,8));
      float mn = fmaxf(m_run[j], rm);
      float al = __expf(m_run[j] - mn);
      m_run[j] = mn;
      float sum = 0.f;
      #pragma unroll
      for (int ni=0;ni<4;ni++){
        float p = __expf(sv[ni][j] - mn);
        sv[ni][j] = p;
        sum += p;
      }
      sum += __shfl_xor(sum,1); sum += __shfl_xor(sum,2);
      sum += __shfl_xor(sum,4); sum += __shfl_xor(sum,8);
      l_run[j] = l_run[j]*al + sum;
      #pragma unroll
      for (int dn=0;dn<4;dn++) o_loc[dn][j] *= al;
    }
    // P -> LDS (bf16, swizzled), C-layout write / A-layout read
    #pragma unroll
    for (int ni=0;ni<4;ni++){
      #pragma unroll
      for (int j=0;j<4;j++){
        int row = (lane>>4)*4 + j, col = ni*16 + (lane&15);
        *(short*)((char*)Psm[w] + row*128 + ((2*col) ^ ((row&7)<<4))) = f2bf(sv[ni][j]);
      }
    }
    // PV (local) + supplied branch (A-frags straight from global fp32)
    #pragma unroll
    for (int kc=0;kc<2;kc++){
      int prow = lane & 15;
      short8 pf = *(const short8*)((const char*)Psm[w] + prow*128 + ((kc*64 + ((lane>>4)*16)) ^ ((prow&7)<<4)));
      int q  = q0w + (lane&15);
      int kb = k0 + kc*32 + (lane>>4)*8;
      const float* sp = supq + (size_t)q*1024 + kb;
      f32x4 s0 = *(const f32x4*)sp;
      f32x4 s1 = *(const f32x4*)(sp+4);
      short8 sf;
      #pragma unroll
      for (int e=0;e<8;e++){
        float vv = (e<4) ? s0[e] : s1[e-4];
        sf[e] = (kb + e > q) ? (short)0 : f2bf(vv);
      }
      #pragma unroll
      for (int dn=0;dn<4;dn++){
        int vrow = dn*16 + (lane&15);
        short8 vf = *(const short8*)((const char*)Vsm + vrow*128 + ((kc*64 + ((lane>>4)*16)) ^ ((vrow&7)<<4)));
        o_loc[dn] = MFMA16(pf, vf, o_loc[dn]);
        o_sup[dn] = MFMA16(sf, vf, o_sup[dn]);
      }
    }
  };

  loadKV(0, rk, rv);
  for (int t=0;;){
    __syncthreads();
    storeKV(rk, rv);
    __syncthreads();
    if (t < qb) loadKV(t+1, rk2, rv2);
    compute(t);
    if (++t > qb) break;
    #pragma unroll
    for (int c=0;c<2;c++){ rk[c]=rk2[c]; rv[c]=rv2[c]; }
  }

  #pragma unroll
  for (int dn=0;dn<4;dn++){
    #pragma unroll
    for (int j=0;j<4;j++){
      int q = q0w + (lane>>4)*4 + j;
      int d = dn*16 + (lane&15);
      float v = 0.5f*o_loc[dn][j]/l_run[j] + 0.5f*o_sup[dn][j];
      ctx[((size_t)b*1024 + q)*1024 + h*64 + d] = f2bf(v);
    }
  }
}

// ---------------- launch ----------------
extern "C" void kernel_launch(void* const* d_in, const int* in_sizes, int n_in,
                              void* d_out, int out_size, void* d_ws, size_t ws_size,
                              hipStream_t stream) {
  const float* query = (const float*)d_in[0];
  const float* key   = (const float*)d_in[1];
  const float* value = (const float*)d_in[2];
  const float* amask = (const float*)d_in[3];
  const float* sup   = (const float*)d_in[4];
  const float* Wq    = (const float*)d_in[5];
  const float* Wk    = (const float*)d_in[6];
  const float* Wv    = (const float*)d_in[7];
  const float* Wo    = (const float*)d_in[8];
  const float* bo    = (const float*)d_in[9];
  // d_in[10] = causal_mask (deterministically triu(1)) -- computed analytically.

  char* ws = (char*)d_ws;
  const size_t MB = 1u<<20;
  short* WqT = (short*)(ws + 0*MB);
  short* WkT = (short*)(ws + 2*MB);
  short* WvT = (short*)(ws + 4*MB);
  short* WoT = (short*)(ws + 6*MB);
  short* Qh  = (short*)(ws + 8*MB);    // [64][1024][64] bf16
  short* Kh  = (short*)(ws + 16*MB);   // [64][1024][64]
  short* VTh = (short*)(ws + 24*MB);   // [64][64][1024]
  short* Ctx = (short*)(ws + 32*MB);   // [4096][1024]
  // total 40 MB of d_ws

  dim3 tb(32,8), tg(32,32);
  transpose_cvt_kernel<<<tg, tb, 0, stream>>>(Wq, WqT);
  transpose_cvt_kernel<<<tg, tb, 0, stream>>>(Wk, WkT);
  transpose_cvt_kernel<<<tg, tb, 0, stream>>>(Wv, WvT);
  transpose_cvt_kernel<<<tg, tb, 0, stream>>>(Wo, WoT);

  dim3 gg(8, 32); // N/128, M/128
  gemm_kernel<true><<<gg, 256, 0, stream>>>(query, WqT, Qh,  nullptr, nullptr, 0);
  gemm_kernel<true><<<gg, 256, 0, stream>>>(key,   WkT, Kh,  nullptr, nullptr, 1);
  gemm_kernel<true><<<gg, 256, 0, stream>>>(value, WvT, VTh, nullptr, nullptr, 2);

  dim3 ga(16, 64); // qblocks, b*h
  attn_kernel<<<ga, 256, 0, stream>>>(Qh, Kh, VTh, amask, sup, Ctx);

  gemm_kernel<false><<<gg, 256, 0, stream>>>(Ctx, WoT, nullptr, (float*)d_out, bo, 3);
}